// Round 4
// baseline (490.796 us; speedup 1.0000x reference)
//
#include <hip/hip_runtime.h>
#include <hip/hip_fp16.h>

#define B_ 128
#define T_ 128
#define I_ 1024
#define O_ 1024
#define M_ (B_*T_)          // 16384 rows of h
#define NOUT (M_*O_)        // 16777216 spike outputs, loss at index NOUT

typedef __attribute__((ext_vector_type(8))) _Float16 half8;    // 8 fp16 = 4 VGPR
typedef __attribute__((ext_vector_type(16))) float floatx16;   // 32x32 MFMA acc

// async global->LDS, 16B per lane. LDS dest = wave-uniform base + lane*16.
__device__ __forceinline__ void gld_lds16(const void* g, void* l) {
    __builtin_amdgcn_global_load_lds((const __attribute__((address_space(1))) void*)g,
                                     (__attribute__((address_space(3))) void*)l,
                                     16, 0, 0);
}

// Workgroup barrier that waits ONLY on LDS ops (lgkmcnt(0)); does NOT drain
// vmcnt. 0xC07F = vmcnt 63 (bits 3:0 & 15:14), expcnt 7, lgkmcnt 0.
__device__ __forceinline__ void barrier_lds_only() {
    asm volatile("" ::: "memory");
    __builtin_amdgcn_s_waitcnt(0xC07F);
    __builtin_amdgcn_s_barrier();
    asm volatile("" ::: "memory");
}

// Exact 3-way FP16 split: x = h + m + l + r with |r| <~ max(2^-33|x|, 2^-26).
// 6 kept cross-products (hh, hm, mh, mm, hl, lh) carry everything down to
// 2^-22 relative; dropped terms (ml, lm, ll) are <= 2^-33.
__device__ __forceinline__ void split3h(float x, unsigned short& h,
                                        unsigned short& m, unsigned short& l) {
    __half f0 = __float2half(x);
    float r1 = x - __half2float(f0);
    __half f1 = __float2half(r1);
    float r2 = r1 - __half2float(f1);
    __half f2 = __float2half(r2);
    h = __half_as_ushort(f0);
    m = __half_as_ushort(f1);
    l = __half_as_ushort(f2);
}

// ---------------------------------------------------------------------------
// split_x: x [M,K] f32 -> 3 fp16 planes, same layout. Pure memory pass.
// ---------------------------------------------------------------------------
__global__ __launch_bounds__(256) void split_x(const float* __restrict__ X,
                                               unsigned short* __restrict__ Xh,
                                               unsigned short* __restrict__ Xm,
                                               unsigned short* __restrict__ Xl) {
    size_t base = ((size_t)blockIdx.x * 256 + threadIdx.x) * 4;
    float4 v = *(const float4*)(X + base);
    ushort4 hh, mm, ll;
    split3h(v.x, hh.x, mm.x, ll.x);
    split3h(v.y, hh.y, mm.y, ll.y);
    split3h(v.z, hh.z, mm.z, ll.z);
    split3h(v.w, hh.w, mm.w, ll.w);
    *(ushort4*)(Xh + base) = hh;
    *(ushort4*)(Xm + base) = mm;
    *(ushort4*)(Xl + base) = ll;
}

// ---------------------------------------------------------------------------
// split_wt: w [K][N] f32 -> three TRANSPOSED fp16 planes wt_p[N][K].
// ---------------------------------------------------------------------------
__global__ __launch_bounds__(256) void split_wt(const float* __restrict__ W,
                                                unsigned short* __restrict__ WTh,
                                                unsigned short* __restrict__ WTm,
                                                unsigned short* __restrict__ WTl) {
    __shared__ float t[64][65];
    const int tid = threadIdx.x;
    const int tx = tid & 63, ty4 = tid >> 6;
    const int r0 = blockIdx.x * 64, c0 = blockIdx.y * 64;
#pragma unroll
    for (int j = 0; j < 16; ++j) {
        int row = j * 4 + ty4;
        t[row][tx] = W[(size_t)(r0 + row) * O_ + c0 + tx];
    }
    __syncthreads();
#pragma unroll
    for (int j = 0; j < 16; ++j) {
        int i = j * 4 + ty4;
        float v = t[tx][i];
        unsigned short h, m, l;
        split3h(v, h, m, l);
        size_t off = (size_t)(c0 + i) * I_ + r0 + tx;
        WTh[off] = h; WTm[off] = m; WTl[off] = l;
    }
}

// ---------------------------------------------------------------------------
// h = x @ w, fp16 3-way-split MFMA, 6 of 9 plane products (hh,hm,mh,mm,hl,lh).
// 128x256 tile, 512 threads, 8 waves x (64x64 output), double-buffered
// 6-plane LDS (2 x 72 KB = 144 KB, 1 block/CU). Stage for kt+1 issued at the
// top of kt's body -> vmcnt(0) at kt+1's top has a full MFMA phase of slack.
// NEW (r4): v_mfma_f32_32x32x16_f16 instead of 16x16x32 — same FLOPs in
// ~17% fewer matrix-pipe cycles (2495 vs 2075 TF ubench class) and half the
// MFMA instruction count. LDS bytes/K-step unchanged (24 ds_read_b128/wave);
// XOR chunk swizzle still makes each 8-lane group cover all 32 banks -> 0
// conflicts. A/B frag: row(col)=lane&31, k=(lane>>5)*8+i. C/D: col=lane&31,
// row=(reg&3)+8*(reg>>2)+4*(lane>>5)  [m74/m101-verified mapping].
// ---------------------------------------------------------------------------
__global__ __launch_bounds__(512, 2) void gemm_h_mfma(
        const unsigned short* __restrict__ Xh, const unsigned short* __restrict__ Xm,
        const unsigned short* __restrict__ Xl, const unsigned short* __restrict__ WTh,
        const unsigned short* __restrict__ WTm, const unsigned short* __restrict__ WTl,
        float* __restrict__ H) {
    const int K = I_, N = O_;
    __shared__ unsigned short P[2][36864];

    const int tid = threadIdx.x;
    const int lane = tid & 63;
    const int wid = tid >> 6;             // 0..7
    const int wrow = wid >> 2;            // 0..1 -> rows wrow*64
    const int wcol = wid & 3;             // 0..3 -> cols wcol*64
    const int l31 = lane & 31;
    const int khalf = lane >> 5;          // 0/1 -> k-offset khalf*8
    const int bm = blockIdx.x * 128, bn = blockIdx.y * 256;

    const int srow = tid >> 2, sch = tid & 3;
    const int schg = sch ^ ((srow >> 1) & 3);
    const unsigned short* gsrcA[3];
    const unsigned short* gsrcB[3];
    gsrcA[0] = Xh  + (size_t)(bm + srow) * K + schg * 8;
    gsrcA[1] = Xm  + (size_t)(bm + srow) * K + schg * 8;
    gsrcA[2] = Xl  + (size_t)(bm + srow) * K + schg * 8;
    gsrcB[0] = WTh + (size_t)(bn + srow) * K + schg * 8;
    gsrcB[1] = WTm + (size_t)(bn + srow) * K + schg * 8;
    gsrcB[2] = WTl + (size_t)(bn + srow) * K + schg * 8;

    auto stage = [&](int kt) {
        unsigned short* wb = &P[0][0] + (size_t)(kt & 1) * 36864;
        const size_t k0 = (size_t)kt * 32;
#pragma unroll
        for (int p = 0; p < 3; ++p)
            gld_lds16(gsrcA[p] + k0, wb + p * 4096 + tid * 8);
#pragma unroll
        for (int p = 0; p < 3; ++p) {
            unsigned short* bb = wb + 12288 + p * 8192 + tid * 8;
            gld_lds16(gsrcB[p] + k0, bb);
            gld_lds16(gsrcB[p] + (size_t)128 * K + k0, bb + 4096);
        }
    };

    floatx16 acc[2][2];
#pragma unroll
    for (int mt = 0; mt < 2; ++mt)
#pragma unroll
        for (int nt = 0; nt < 2; ++nt) acc[mt][nt] = (floatx16)(0.f);

    stage(0);   // prologue

    for (int kt = 0; kt < 32; ++kt) {
        const unsigned short* rb = &P[0][0] + (size_t)(kt & 1) * 36864;

        asm volatile("" ::: "memory");
        __builtin_amdgcn_s_waitcnt(0x1F70);   // vmcnt(0), lgkm/exp no-wait
        __builtin_amdgcn_s_barrier();
        asm volatile("" ::: "memory");

        // A fragments: 3 planes x 2 row-tiles x 2 k-slices
        half8 Af[3][2][2];
#pragma unroll
        for (int pa = 0; pa < 3; ++pa)
#pragma unroll
            for (int mt = 0; mt < 2; ++mt) {
                const int row = wrow * 64 + mt * 32 + l31;
                const int sw = (row >> 1) & 3;
#pragma unroll
                for (int ks = 0; ks < 2; ++ks) {
                    const int chk = (ks * 2 + khalf) ^ sw;
                    Af[pa][mt][ks] = *(const half8*)(rb + pa * 4096 + row * 32 + chk * 8);
                }
            }

        if (kt < 31) stage(kt + 1);   // in flight across this step's MFMAs

#pragma unroll
        for (int pb = 0; pb < 3; ++pb) {
            half8 Bf[2][2];
#pragma unroll
            for (int nt = 0; nt < 2; ++nt) {
                const int col = wcol * 64 + nt * 32 + l31;
                const int sw = (col >> 1) & 3;
#pragma unroll
                for (int ks = 0; ks < 2; ++ks) {
                    const int chk = (ks * 2 + khalf) ^ sw;
                    Bf[nt][ks] = *(const half8*)(rb + 12288 + pb * 8192 + col * 32 + chk * 8);
                }
            }
#pragma unroll
            for (int nt = 0; nt < 2; ++nt)
#pragma unroll
                for (int mt = 0; mt < 2; ++mt)
#pragma unroll
                    for (int ks = 0; ks < 2; ++ks) {
                        acc[mt][nt] = __builtin_amdgcn_mfma_f32_32x32x16_f16(Af[0][mt][ks], Bf[nt][ks], acc[mt][nt], 0, 0, 0);
                        if (pb < 2)
                            acc[mt][nt] = __builtin_amdgcn_mfma_f32_32x32x16_f16(Af[1][mt][ks], Bf[nt][ks], acc[mt][nt], 0, 0, 0);
                        if (pb == 0)
                            acc[mt][nt] = __builtin_amdgcn_mfma_f32_32x32x16_f16(Af[2][mt][ks], Bf[nt][ks], acc[mt][nt], 0, 0, 0);
                    }
        }
    }

    // epilogue: C/D col = lane&31, row = (reg&3) + 8*(reg>>2) + 4*(lane>>5)
#pragma unroll
    for (int mt = 0; mt < 2; ++mt)
#pragma unroll
        for (int nt = 0; nt < 2; ++nt) {
            const int gcol = bn + wcol * 64 + nt * 32 + l31;
#pragma unroll
            for (int r = 0; r < 16; ++r) {
                const int grow = bm + wrow * 64 + mt * 32 + (r & 3) + 8 * (r >> 2) + 4 * khalf;
                H[(size_t)grow * N + gcol] = acc[mt][nt][r];
            }
        }
}

// ---------------------------------------------------------------------------
// d = w^T w   (fp32 exact-class — kept exact deliberately: d feeds 128
// accumulating reset steps in the scan; restored after the r3 MFMA-reuse
// attempt ran on only 32 blocks = 12.5% CU utilization, ~80us vs this 25us).
// ---------------------------------------------------------------------------
__global__ __launch_bounds__(256) void gemm_wtw(const float* __restrict__ W,
                                                float* __restrict__ D) {
    const int K = I_, N = O_;
    __shared__ float As[32][68];
    __shared__ float Bs[32][68];
    const int tid = threadIdx.x;
    const int tx = tid & 15, ty = tid >> 4;
    const int bj = blockIdx.x * 64, bo = blockIdx.y * 64;
    const int lr = tid >> 4;
    const int lc = (tid & 15) << 2;

    float acc[4][4];
#pragma unroll
    for (int m = 0; m < 4; m++)
#pragma unroll
        for (int n = 0; n < 4; n++) acc[m][n] = 0.f;

    for (int k0 = 0; k0 < K; k0 += 32) {
        float4 a0 = *(const float4*)(W + (size_t)(k0 + lr) * N + bj + lc);
        float4 a1 = *(const float4*)(W + (size_t)(k0 + lr + 16) * N + bj + lc);
        float4 b0 = *(const float4*)(W + (size_t)(k0 + lr) * N + bo + lc);
        float4 b1 = *(const float4*)(W + (size_t)(k0 + lr + 16) * N + bo + lc);
        __syncthreads();
        *(float4*)&As[lr][lc] = a0; *(float4*)&As[lr + 16][lc] = a1;
        *(float4*)&Bs[lr][lc] = b0; *(float4*)&Bs[lr + 16][lc] = b1;
        __syncthreads();
#pragma unroll
        for (int k = 0; k < 32; ++k) {
            float4 av = *(const float4*)&As[k][ty * 4];
            float4 bv = *(const float4*)&Bs[k][tx * 4];
            float am[4] = {av.x, av.y, av.z, av.w};
            float bb[4] = {bv.x, bv.y, bv.z, bv.w};
#pragma unroll
            for (int m = 0; m < 4; m++)
#pragma unroll
                for (int n = 0; n < 4; n++) acc[m][n] += am[m] * bb[n];
        }
    }
#pragma unroll
    for (int m = 0; m < 4; m++) {
        float4 v = make_float4(acc[m][0], acc[m][1], acc[m][2], acc[m][3]);
        *(float4*)(D + (size_t)(bj + ty * 4 + m) * N + bo + tx * 4) = v;
    }
}

// inv_norm[o] = 1/(d[o][o] + 1e-8); also zero the spike counter.
__global__ void colnorm_diag(const float* __restrict__ D, float* __restrict__ invn,
                             unsigned int* __restrict__ counter) {
    int o = blockIdx.x * 256 + threadIdx.x;
    if (o == 0) *counter = 0u;
    invn[o] = 1.0f / (D[(size_t)o * O_ + o] + 1e-8f);
}

// ---------------------------------------------------------------------------
// Sequential scan: 512 threads/block, thread owns 2 contiguous neurons
// (float2) — 8 waves/CU for latency hiding on the per-step L2 gather of
// d-rows. ONE LDS-only barrier per step; ballot-aggregated appends with a
// single lane-0 LDS atomicAdd + shfl per wave.
// Race-safety: barrier every step; step-t appends -> lst[(t+1)&1], step-t
// reads <- lst[t&1] (disjoint between consecutive barriers).
// ---------------------------------------------------------------------------
__global__ __launch_bounds__(512) void scan_kernel(const float* __restrict__ h,
                                                   const float* __restrict__ d,
                                                   const float* __restrict__ invn,
                                                   const float* __restrict__ bias,
                                                   const float* __restrict__ beta,
                                                   float* __restrict__ out,
                                                   unsigned int* __restrict__ spike_count) {
    __shared__ int lst[2][O_];
    __shared__ int cnt[T_ + 1];
    __shared__ unsigned int red[512];

    const int tid = threadIdx.x;
    const int lane = tid & 63;
    const int b = blockIdx.x;
    const int o2 = tid * 2;
    const float betav = beta[0];
    const float omb = 1.0f - betav;

    const float2 invn2 = *(const float2*)(invn + o2);
    const float2 b2 = *(const float2*)(bias + o2);
    float2 mem2 = make_float2(0.f, 0.f);

    for (int i = tid; i <= T_; i += 512) cnt[i] = 0;
    unsigned int local_count = 0;
    const float* hb = h + (size_t)b * T_ * O_;
    float* ob = out + (size_t)b * T_ * O_;
    const unsigned long long below = (lane == 63) ? 0xFFFFFFFFFFFFFFFFull >> 1
                                                  : ((1ull << lane) - 1ull);

    float2 hcur = *(const float2*)(hb + o2);   // t = 0
    __syncthreads();

    for (int t = 0; t < T_; ++t) {
        const int p = t & 1, q = p ^ 1;
        const int n = cnt[t];

        float2 hnext = make_float2(0.f, 0.f);
        if (t + 1 < T_) hnext = *(const float2*)(hb + (size_t)(t + 1) * O_ + o2);

        float2 rst = make_float2(0.f, 0.f);
        int i = 0;
        for (; i + 16 <= n; i += 16) {
            float2 v[16];
#pragma unroll
            for (int u = 0; u < 16; ++u) {
                const int j = lst[p][i + u];
                v[u] = *(const float2*)(d + (size_t)j * O_ + o2);
            }
#pragma unroll
            for (int u = 0; u < 16; ++u) { rst.x += v[u].x; rst.y += v[u].y; }
        }
        for (; i + 4 <= n; i += 4) {
            float2 v[4];
#pragma unroll
            for (int u = 0; u < 4; ++u) {
                const int j = lst[p][i + u];
                v[u] = *(const float2*)(d + (size_t)j * O_ + o2);
            }
#pragma unroll
            for (int u = 0; u < 4; ++u) { rst.x += v[u].x; rst.y += v[u].y; }
        }
        for (; i < n; ++i) {
            const int j = lst[p][i];
            float2 v = *(const float2*)(d + (size_t)j * O_ + o2);
            rst.x += v.x; rst.y += v.y;
        }

        mem2.x = (mem2.x - rst.x) * betav + hcur.x * omb;
        mem2.y = (mem2.y - rst.y) * betav + hcur.y * omb;

        const int s0 = (mem2.x * invn2.x - b2.x) > 0.0f;
        const int s1 = (mem2.y * invn2.y - b2.y) > 0.0f;

        float2 sv = make_float2(s0 ? 1.f : 0.f, s1 ? 1.f : 0.f);
        *(float2*)(ob + (size_t)t * O_ + o2) = sv;
        local_count += (unsigned)(s0 + s1);

        // ballot-aggregated appends into lst[q] / cnt[t+1]: ONE atomic per wave
        unsigned long long mk0 = __ballot(s0);
        unsigned long long mk1 = __ballot(s1);
        const int c0 = __popcll(mk0);
        const int tot = c0 + __popcll(mk1);
        int base = 0;
        if (lane == 0 && tot) base = atomicAdd(&cnt[t + 1], tot);
        base = __shfl(base, 0, 64);
        if (s0) lst[q][base + __popcll(mk0 & below)] = o2 + 0;
        base += c0;
        if (s1) lst[q][base + __popcll(mk1 & below)] = o2 + 1;

        barrier_lds_only();
        hcur = hnext;
    }

    red[tid] = local_count;
    __syncthreads();
    for (int st = 256; st > 0; st >>= 1) {
        if (tid < st) red[tid] += red[tid + st];
        __syncthreads();
    }
    if (tid == 0) atomicAdd(spike_count, red[0]);
}

__global__ void finalize_loss(const unsigned int* __restrict__ spike_count,
                              float* __restrict__ loss_out) {
    *loss_out = 0.5f * ((float)(*spike_count) / 16777216.0f);
}

// ---------------------------------------------------------------------------
extern "C" void kernel_launch(void* const* d_in, const int* in_sizes, int n_in,
                              void* d_out, int out_size, void* d_ws, size_t ws_size,
                              hipStream_t stream) {
    const float* x    = (const float*)d_in[0];   // [B,T,I]
    const float* w    = (const float*)d_in[1];   // [I,O]
    const float* beta = (const float*)d_in[2];   // [1]
    const float* bias = (const float*)d_in[3];   // [O]
    float* out = (float*)d_out;                  // NOUT spikes + 1 loss

    // workspace layout (~170 MB)
    char* ws = (char*)d_ws;
    float* h    = (float*)ws;                                         // 64 MiB
    float* dmat = (float*)(ws + (size_t)67108864);                    // 4 MiB
    float* invn = (float*)(ws + (size_t)71303168);                    // 4 KiB
    unsigned int* cntp = (unsigned int*)(ws + (size_t)71307264);      // 4 KiB
    unsigned short* wt_h = (unsigned short*)(ws + (size_t)71311360);  // 2 MiB
    unsigned short* wt_m = (unsigned short*)(ws + (size_t)73408512);  // 2 MiB
    unsigned short* wt_l = (unsigned short*)(ws + (size_t)75505664);  // 2 MiB
    unsigned short* x_h  = (unsigned short*)(ws + (size_t)77602816);  // 32 MiB
    unsigned short* x_m  = (unsigned short*)(ws + (size_t)111157248); // 32 MiB
    unsigned short* x_l  = (unsigned short*)(ws + (size_t)144711680); // 32 MiB

    split_x<<<M_ * I_ / 1024, 256, 0, stream>>>(x, x_h, x_m, x_l);
    split_wt<<<dim3(I_ / 64, O_ / 64), 256, 0, stream>>>(w, wt_h, wt_m, wt_l);
    gemm_h_mfma<<<dim3(M_ / 128, O_ / 256), 512, 0, stream>>>(x_h, x_m, x_l,
                                                              wt_h, wt_m, wt_l, h);
    gemm_wtw<<<dim3(O_ / 64, O_ / 64), 256, 0, stream>>>(w, dmat);
    colnorm_diag<<<O_ / 256, 256, 0, stream>>>(dmat, invn, cntp);
    scan_kernel<<<B_, 512, 0, stream>>>(h, dmat, invn, bias, beta, out, cntp);
    finalize_loss<<<1, 1, 0, stream>>>(cntp, out + (size_t)NOUT);
}

// Round 5
// 465.555 us; speedup vs baseline: 1.0542x; 1.0542x over previous
//
#include <hip/hip_runtime.h>
#include <hip/hip_fp16.h>

#define B_ 128
#define T_ 128
#define I_ 1024
#define O_ 1024
#define M_ (B_*T_)          // 16384 rows of h
#define NOUT (M_*O_)        // 16777216 spike outputs, loss at index NOUT

typedef __attribute__((ext_vector_type(8))) _Float16 half8;  // 8 fp16 = 4 VGPR
typedef __attribute__((ext_vector_type(4))) float floatx4;   // MFMA acc

// async global->LDS, 16B per lane. LDS dest = wave-uniform base + lane*16.
__device__ __forceinline__ void gld_lds16(const void* g, void* l) {
    __builtin_amdgcn_global_load_lds((const __attribute__((address_space(1))) void*)g,
                                     (__attribute__((address_space(3))) void*)l,
                                     16, 0, 0);
}

// Workgroup barrier that waits ONLY on LDS ops (lgkmcnt(0)); does NOT drain
// vmcnt. 0xC07F = vmcnt 63 (bits 3:0 & 15:14), expcnt 7, lgkmcnt 0.
__device__ __forceinline__ void barrier_lds_only() {
    asm volatile("" ::: "memory");
    __builtin_amdgcn_s_waitcnt(0xC07F);
    __builtin_amdgcn_s_barrier();
    asm volatile("" ::: "memory");
}

// Exact 3-way FP16 split: x = h + m + l + r with |r| <~ max(2^-33|x|, 2^-26).
// 6 kept cross-products (hh, hm, mh, mm, hl, lh) carry everything down to
// 2^-22 relative; dropped terms (ml, lm, ll) are <= 2^-33.
__device__ __forceinline__ void split3h(float x, unsigned short& h,
                                        unsigned short& m, unsigned short& l) {
    __half f0 = __float2half(x);
    float r1 = x - __half2float(f0);
    __half f1 = __float2half(r1);
    float r2 = r1 - __half2float(f1);
    __half f2 = __float2half(r2);
    h = __half_as_ushort(f0);
    m = __half_as_ushort(f1);
    l = __half_as_ushort(f2);
}

// ---------------------------------------------------------------------------
// split_x: x [M,K] f32 -> 3 fp16 planes, same layout. Pure memory pass.
// ---------------------------------------------------------------------------
__global__ __launch_bounds__(256) void split_x(const float* __restrict__ X,
                                               unsigned short* __restrict__ Xh,
                                               unsigned short* __restrict__ Xm,
                                               unsigned short* __restrict__ Xl) {
    size_t base = ((size_t)blockIdx.x * 256 + threadIdx.x) * 4;
    float4 v = *(const float4*)(X + base);
    ushort4 hh, mm, ll;
    split3h(v.x, hh.x, mm.x, ll.x);
    split3h(v.y, hh.y, mm.y, ll.y);
    split3h(v.z, hh.z, mm.z, ll.z);
    split3h(v.w, hh.w, mm.w, ll.w);
    *(ushort4*)(Xh + base) = hh;
    *(ushort4*)(Xm + base) = mm;
    *(ushort4*)(Xl + base) = ll;
}

// ---------------------------------------------------------------------------
// split_wt: w [K][N] f32 -> three TRANSPOSED fp16 planes wt_p[N][K].
// ---------------------------------------------------------------------------
__global__ __launch_bounds__(256) void split_wt(const float* __restrict__ W,
                                                unsigned short* __restrict__ WTh,
                                                unsigned short* __restrict__ WTm,
                                                unsigned short* __restrict__ WTl) {
    __shared__ float t[64][65];
    const int tid = threadIdx.x;
    const int tx = tid & 63, ty4 = tid >> 6;
    const int r0 = blockIdx.x * 64, c0 = blockIdx.y * 64;
#pragma unroll
    for (int j = 0; j < 16; ++j) {
        int row = j * 4 + ty4;
        t[row][tx] = W[(size_t)(r0 + row) * O_ + c0 + tx];
    }
    __syncthreads();
#pragma unroll
    for (int j = 0; j < 16; ++j) {
        int i = j * 4 + ty4;
        float v = t[tx][i];
        unsigned short h, m, l;
        split3h(v, h, m, l);
        size_t off = (size_t)(c0 + i) * I_ + r0 + tx;
        WTh[off] = h; WTm[off] = m; WTl[off] = l;
    }
}

// ---------------------------------------------------------------------------
// h = x @ w, fp16 3-way-split MFMA, 6 of 9 plane products (hh,hm,mh,mm,hl,lh).
// 128x256 tile, 512 threads, 8 waves x (64x64 output), double-buffered
// 6-plane LDS (2 x 72 KB = 144 KB, 1 block/CU). Stage for kt+1 issued at the
// top of kt's body -> vmcnt(0) at kt+1's top has a full MFMA phase of slack.
// REVERTED (r5) to the 16x16x32 shape: the r4 32x32x16 fragment pattern broke
// the XOR swizzle (SQ_LDS_BANK_CONFLICT 0 -> 1.26e7, 160 -> 181 us). This
// exact version measured 160.1 us / MfmaUtil 59% / 0 conflicts twice (r2,r3).
// ---------------------------------------------------------------------------
__global__ __launch_bounds__(512, 2) void gemm_h_mfma(
        const unsigned short* __restrict__ Xh, const unsigned short* __restrict__ Xm,
        const unsigned short* __restrict__ Xl, const unsigned short* __restrict__ WTh,
        const unsigned short* __restrict__ WTm, const unsigned short* __restrict__ WTl,
        float* __restrict__ H) {
    const int K = I_, N = O_;
    __shared__ unsigned short P[2][36864];

    const int tid = threadIdx.x;
    const int lane = tid & 63;
    const int wid = tid >> 6;             // 0..7
    const int wrow = wid >> 2;            // 0..1 -> rows wrow*64
    const int wcol = wid & 3;             // 0..3 -> cols wcol*64
    const int l15 = lane & 15, quad = lane >> 4;
    const int bm = blockIdx.x * 128, bn = blockIdx.y * 256;

    const int srow = tid >> 2, sch = tid & 3;
    const int schg = sch ^ ((srow >> 1) & 3);
    const unsigned short* gsrcA[3];
    const unsigned short* gsrcB[3];
    gsrcA[0] = Xh  + (size_t)(bm + srow) * K + schg * 8;
    gsrcA[1] = Xm  + (size_t)(bm + srow) * K + schg * 8;
    gsrcA[2] = Xl  + (size_t)(bm + srow) * K + schg * 8;
    gsrcB[0] = WTh + (size_t)(bn + srow) * K + schg * 8;
    gsrcB[1] = WTm + (size_t)(bn + srow) * K + schg * 8;
    gsrcB[2] = WTl + (size_t)(bn + srow) * K + schg * 8;

    auto stage = [&](int kt) {
        unsigned short* wb = &P[0][0] + (size_t)(kt & 1) * 36864;
        const size_t k0 = (size_t)kt * 32;
#pragma unroll
        for (int p = 0; p < 3; ++p)
            gld_lds16(gsrcA[p] + k0, wb + p * 4096 + tid * 8);
#pragma unroll
        for (int p = 0; p < 3; ++p) {
            unsigned short* bb = wb + 12288 + p * 8192 + tid * 8;
            gld_lds16(gsrcB[p] + k0, bb);
            gld_lds16(gsrcB[p] + (size_t)128 * K + k0, bb + 4096);
        }
    };

    floatx4 acc[4][4];
#pragma unroll
    for (int mt = 0; mt < 4; ++mt)
#pragma unroll
        for (int nt = 0; nt < 4; ++nt) acc[mt][nt] = (floatx4)(0.f);

    stage(0);   // prologue

    for (int kt = 0; kt < 32; ++kt) {
        const unsigned short* rb = &P[0][0] + (size_t)(kt & 1) * 36864;

        asm volatile("" ::: "memory");
        __builtin_amdgcn_s_waitcnt(0x1F70);   // vmcnt(0), lgkm/exp no-wait
        __builtin_amdgcn_s_barrier();
        asm volatile("" ::: "memory");

        half8 Af[3][4];
#pragma unroll
        for (int pa = 0; pa < 3; ++pa)
#pragma unroll
            for (int mt = 0; mt < 4; ++mt) {
                const int row = wrow * 64 + mt * 16 + l15;
                const int chk = quad ^ ((row >> 1) & 3);
                Af[pa][mt] = *(const half8*)(rb + pa * 4096 + row * 32 + chk * 8);
            }

        if (kt < 31) stage(kt + 1);   // in flight across this step's MFMAs

#pragma unroll
        for (int pb = 0; pb < 3; ++pb) {
            half8 Bf[4];
#pragma unroll
            for (int nt = 0; nt < 4; ++nt) {
                const int col = wcol * 64 + nt * 16 + l15;
                const int chk = quad ^ ((col >> 1) & 3);
                Bf[nt] = *(const half8*)(rb + 12288 + pb * 8192 + col * 32 + chk * 8);
            }
#pragma unroll
            for (int nt = 0; nt < 4; ++nt)
#pragma unroll
                for (int mt = 0; mt < 4; ++mt) {
                    acc[mt][nt] = __builtin_amdgcn_mfma_f32_16x16x32_f16(Af[0][mt], Bf[nt], acc[mt][nt], 0, 0, 0);
                    if (pb < 2)
                        acc[mt][nt] = __builtin_amdgcn_mfma_f32_16x16x32_f16(Af[1][mt], Bf[nt], acc[mt][nt], 0, 0, 0);
                    if (pb == 0)
                        acc[mt][nt] = __builtin_amdgcn_mfma_f32_16x16x32_f16(Af[2][mt], Bf[nt], acc[mt][nt], 0, 0, 0);
                }
        }
    }

    // epilogue: C/D row = quad*4 + reg, col = lane&15
#pragma unroll
    for (int mt = 0; mt < 4; ++mt)
#pragma unroll
        for (int nt = 0; nt < 4; ++nt) {
            int grow = bm + wrow * 64 + mt * 16 + quad * 4;
            int gcol = bn + wcol * 64 + nt * 16 + l15;
            float* hp = H + (size_t)grow * N + gcol;
#pragma unroll
            for (int r = 0; r < 4; ++r) hp[(size_t)r * N] = acc[mt][nt][r];
        }
}

// ---------------------------------------------------------------------------
// d = w^T w   (fp32 exact-class, 256 blocks, ~25 us measured).
// ---------------------------------------------------------------------------
__global__ __launch_bounds__(256) void gemm_wtw(const float* __restrict__ W,
                                                float* __restrict__ D) {
    const int K = I_, N = O_;
    __shared__ float As[32][68];
    __shared__ float Bs[32][68];
    const int tid = threadIdx.x;
    const int tx = tid & 15, ty = tid >> 4;
    const int bj = blockIdx.x * 64, bo = blockIdx.y * 64;
    const int lr = tid >> 4;
    const int lc = (tid & 15) << 2;

    float acc[4][4];
#pragma unroll
    for (int m = 0; m < 4; m++)
#pragma unroll
        for (int n = 0; n < 4; n++) acc[m][n] = 0.f;

    for (int k0 = 0; k0 < K; k0 += 32) {
        float4 a0 = *(const float4*)(W + (size_t)(k0 + lr) * N + bj + lc);
        float4 a1 = *(const float4*)(W + (size_t)(k0 + lr + 16) * N + bj + lc);
        float4 b0 = *(const float4*)(W + (size_t)(k0 + lr) * N + bo + lc);
        float4 b1 = *(const float4*)(W + (size_t)(k0 + lr + 16) * N + bo + lc);
        __syncthreads();
        *(float4*)&As[lr][lc] = a0; *(float4*)&As[lr + 16][lc] = a1;
        *(float4*)&Bs[lr][lc] = b0; *(float4*)&Bs[lr + 16][lc] = b1;
        __syncthreads();
#pragma unroll
        for (int k = 0; k < 32; ++k) {
            float4 av = *(const float4*)&As[k][ty * 4];
            float4 bv = *(const float4*)&Bs[k][tx * 4];
            float am[4] = {av.x, av.y, av.z, av.w};
            float bb[4] = {bv.x, bv.y, bv.z, bv.w};
#pragma unroll
            for (int m = 0; m < 4; m++)
#pragma unroll
                for (int n = 0; n < 4; n++) acc[m][n] += am[m] * bb[n];
        }
    }
#pragma unroll
    for (int m = 0; m < 4; m++) {
        float4 v = make_float4(acc[m][0], acc[m][1], acc[m][2], acc[m][3]);
        *(float4*)(D + (size_t)(bj + ty * 4 + m) * N + bo + tx * 4) = v;
    }
}

// inv_norm[o] = 1/(d[o][o] + 1e-8); zero the spike counter; zero the dummy
// gather row (zrow, reused dead x_h region) used by the scan's padded batches.
__global__ void colnorm_diag(const float* __restrict__ D, float* __restrict__ invn,
                             unsigned int* __restrict__ counter,
                             float* __restrict__ zrow) {
    int o = blockIdx.x * 256 + threadIdx.x;
    if (o == 0) *counter = 0u;
    invn[o] = 1.0f / (D[(size_t)o * O_ + o] + 1e-8f);
    zrow[o] = 0.0f;
}

// ---------------------------------------------------------------------------
// Sequential scan: 512 threads/block, thread owns 2 contiguous neurons.
// NEW (r5): the d-row gather runs as ceil(n/8) batches of 8 with reader-side
// zero-row padding — all 8 index reads + 8 L2 row loads issue concurrently.
// Rationale: measured spike counts are small (n ~ 5-10/step), so the old
// 16/4-batches never fired and the scalar tail serialized n x ~300cyc of
// LDS+L2 latency per step (scan ~200us = 3750 cyc/step). Padding loads read
// a zeroed dummy row (exact +0.0, no numeric change).
// Append protocol unchanged (verified): one LDS-only barrier per step;
// ballot-aggregated appends, single lane-0 LDS atomicAdd + shfl per wave.
// Race-safety: barrier every step; step-t appends -> lst[(t+1)&1], step-t
// reads <- lst[t&1] (disjoint between consecutive barriers).
// ---------------------------------------------------------------------------
__global__ __launch_bounds__(512) void scan_kernel(const float* __restrict__ h,
                                                   const float* __restrict__ d,
                                                   const float* __restrict__ invn,
                                                   const float* __restrict__ bias,
                                                   const float* __restrict__ beta,
                                                   const float* __restrict__ zrow,
                                                   float* __restrict__ out,
                                                   unsigned int* __restrict__ spike_count) {
    __shared__ int lst[2][O_];
    __shared__ int cnt[T_ + 1];
    __shared__ unsigned int red[512];

    const int tid = threadIdx.x;
    const int lane = tid & 63;
    const int b = blockIdx.x;
    const int o2 = tid * 2;
    const float betav = beta[0];
    const float omb = 1.0f - betav;

    const float2 invn2 = *(const float2*)(invn + o2);
    const float2 b2 = *(const float2*)(bias + o2);
    float2 mem2 = make_float2(0.f, 0.f);

    for (int i = tid; i <= T_; i += 512) cnt[i] = 0;
    unsigned int local_count = 0;
    const float* hb = h + (size_t)b * T_ * O_;
    float* ob = out + (size_t)b * T_ * O_;
    const float* zp = zrow + o2;
    const unsigned long long below = (lane == 63) ? 0xFFFFFFFFFFFFFFFFull >> 1
                                                  : ((1ull << lane) - 1ull);

    float2 hcur = *(const float2*)(hb + o2);   // t = 0
    __syncthreads();

    for (int t = 0; t < T_; ++t) {
        const int p = t & 1, q = p ^ 1;
        const int n = cnt[t];

        float2 hnext = make_float2(0.f, 0.f);
        if (t + 1 < T_) hnext = *(const float2*)(hb + (size_t)(t + 1) * O_ + o2);

        float2 rst = make_float2(0.f, 0.f);
        for (int i = 0; i < n; i += 8) {
            float2 v[8];
#pragma unroll
            for (int u = 0; u < 8; ++u) {
                const int idx = i + u;
                const int j = lst[p][idx & (O_ - 1)];   // in-bounds read; value
                                                        // only used when idx<n
                const float* src = (idx < n) ? (d + (size_t)j * O_ + o2) : zp;
                v[u] = *(const float2*)src;
            }
#pragma unroll
            for (int u = 0; u < 8; ++u) { rst.x += v[u].x; rst.y += v[u].y; }
        }

        mem2.x = (mem2.x - rst.x) * betav + hcur.x * omb;
        mem2.y = (mem2.y - rst.y) * betav + hcur.y * omb;

        const int s0 = (mem2.x * invn2.x - b2.x) > 0.0f;
        const int s1 = (mem2.y * invn2.y - b2.y) > 0.0f;

        float2 sv = make_float2(s0 ? 1.f : 0.f, s1 ? 1.f : 0.f);
        *(float2*)(ob + (size_t)t * O_ + o2) = sv;
        local_count += (unsigned)(s0 + s1);

        // ballot-aggregated appends into lst[q] / cnt[t+1]: ONE atomic per wave
        unsigned long long mk0 = __ballot(s0);
        unsigned long long mk1 = __ballot(s1);
        const int c0 = __popcll(mk0);
        const int tot = c0 + __popcll(mk1);
        int base = 0;
        if (lane == 0 && tot) base = atomicAdd(&cnt[t + 1], tot);
        base = __shfl(base, 0, 64);
        if (s0) lst[q][base + __popcll(mk0 & below)] = o2 + 0;
        base += c0;
        if (s1) lst[q][base + __popcll(mk1 & below)] = o2 + 1;

        barrier_lds_only();
        hcur = hnext;
    }

    red[tid] = local_count;
    __syncthreads();
    for (int st = 256; st > 0; st >>= 1) {
        if (tid < st) red[tid] += red[tid + st];
        __syncthreads();
    }
    if (tid == 0) atomicAdd(spike_count, red[0]);
}

__global__ void finalize_loss(const unsigned int* __restrict__ spike_count,
                              float* __restrict__ loss_out) {
    *loss_out = 0.5f * ((float)(*spike_count) / 16777216.0f);
}

// ---------------------------------------------------------------------------
extern "C" void kernel_launch(void* const* d_in, const int* in_sizes, int n_in,
                              void* d_out, int out_size, void* d_ws, size_t ws_size,
                              hipStream_t stream) {
    const float* x    = (const float*)d_in[0];   // [B,T,I]
    const float* w    = (const float*)d_in[1];   // [I,O]
    const float* beta = (const float*)d_in[2];   // [1]
    const float* bias = (const float*)d_in[3];   // [O]
    float* out = (float*)d_out;                  // NOUT spikes + 1 loss

    // workspace layout (~170 MB)
    char* ws = (char*)d_ws;
    float* h    = (float*)ws;                                         // 64 MiB
    float* dmat = (float*)(ws + (size_t)67108864);                    // 4 MiB
    float* invn = (float*)(ws + (size_t)71303168);                    // 4 KiB
    unsigned int* cntp = (unsigned int*)(ws + (size_t)71307264);      // 4 KiB
    unsigned short* wt_h = (unsigned short*)(ws + (size_t)71311360);  // 2 MiB
    unsigned short* wt_m = (unsigned short*)(ws + (size_t)73408512);  // 2 MiB
    unsigned short* wt_l = (unsigned short*)(ws + (size_t)75505664);  // 2 MiB
    unsigned short* x_h  = (unsigned short*)(ws + (size_t)77602816);  // 32 MiB
    unsigned short* x_m  = (unsigned short*)(ws + (size_t)111157248); // 32 MiB
    unsigned short* x_l  = (unsigned short*)(ws + (size_t)144711680); // 32 MiB
    float* zrow = (float*)x_h;   // dead after gemm_h; zeroed by colnorm_diag

    split_x<<<M_ * I_ / 1024, 256, 0, stream>>>(x, x_h, x_m, x_l);
    split_wt<<<dim3(I_ / 64, O_ / 64), 256, 0, stream>>>(w, wt_h, wt_m, wt_l);
    gemm_h_mfma<<<dim3(M_ / 128, O_ / 256), 512, 0, stream>>>(x_h, x_m, x_l,
                                                              wt_h, wt_m, wt_l, h);
    gemm_wtw<<<dim3(O_ / 64, O_ / 64), 256, 0, stream>>>(w, dmat);
    colnorm_diag<<<O_ / 256, 256, 0, stream>>>(dmat, invn, cntp, zrow);
    scan_kernel<<<B_, 512, 0, stream>>>(h, dmat, invn, bias, beta, zrow, out, cntp);
    finalize_loss<<<1, 1, 0, stream>>>(cntp, out + (size_t)NOUT);
}